// Round 1
// baseline (248.088 us; speedup 1.0000x reference)
//
#include <hip/hip_runtime.h>

#define B_ 4
#define T_ 2048
#define C_ 1024

typedef unsigned short u16;
typedef unsigned int u32;
typedef short sh8 __attribute__((ext_vector_type(8)));   // 8 bf16 payload (4 VGPRs)
typedef float f32x4 __attribute__((ext_vector_type(4)));

__device__ __forceinline__ float bf2f(u16 u) {
    union { float f; u32 i; } c; c.i = ((u32)u) << 16; return c.f;
}
__device__ __forceinline__ u16 f2bf(float f) {
    union { float f; u32 i; } c; c.f = f;
    return (u16)((c.i + 0x7FFFu + ((c.i >> 16) & 1u)) >> 16);
}

// async 16B/lane global->LDS. Dest = wave-uniform base + lane*16.
__device__ __forceinline__ void gload_lds16(const void* g, void* l) {
    __builtin_amdgcn_global_load_lds(
        (const __attribute__((address_space(1))) u32*)g,
        (__attribute__((address_space(3))) u32*)l, 16, 0, 0);
}

__device__ __forceinline__ void wait_vm8()   { asm volatile("s_waitcnt vmcnt(8)" ::: "memory"); }
__device__ __forceinline__ void wait_vm4()   { asm volatile("s_waitcnt vmcnt(4)" ::: "memory"); }
__device__ __forceinline__ void wait_vm0()   { asm volatile("s_waitcnt vmcnt(0)" ::: "memory"); }
__device__ __forceinline__ void barrier_raw(){ asm volatile("s_barrier" ::: "memory"); }

// ---------------------------------------------------------------------------
// 128x128 TN MFMA core (kept for scores/pv), bf16, BK=64, double-buffered
// global_load_lds with counted vmcnt(8). See previous session notes.
// ---------------------------------------------------------------------------
template<bool RS>
__device__ __forceinline__ void mm_core(
    const u16* __restrict__ A, const u16* __restrict__ B,
    int ldA, int ldB, int nk64,
    u16* lds, f32x4 (&acc)[4][4], f32x4* rsacc, int tid)
{
    const int w  = tid >> 6, l = tid & 63;
    const int fr = l & 15,  fq = l >> 4;
    const int wm = (w & 1) << 6, wn = (w >> 1) << 6;
    const int rl = l >> 3;            // row within 8-row group
    const int pc = l & 7;             // phys granule col this lane fills
    const int cg = pc ^ rl;           // logical granule to fetch

    sh8 ones;
    if (RS) {
#pragma unroll
        for (int e = 0; e < 8; ++e) ones[e] = (short)0x3F80;  // bf16 1.0
    }

    auto issue = [&](int kt) {
        const int ko = kt << 6;
        u16* dA = lds + ((kt & 1) << 14);
        u16* dB = dA + 8192;
#pragma unroll
        for (int t = 0; t < 4; ++t) {
            const int r0 = w * 32 + t * 8;
            const int r  = r0 + rl;
            gload_lds16(A + (size_t)r * ldA + ko + cg * 8, dA + ((size_t)r0 * 8 + l) * 8);
            gload_lds16(B + (size_t)r * ldB + ko + cg * 8, dB + ((size_t)r0 * 8 + l) * 8);
        }
    };

    issue(0);
    issue(1);

    for (int kt = 0; kt < nk64; ++kt) {
        if (kt + 1 < nk64) wait_vm8(); else wait_vm0();
        barrier_raw();                       // block-wide: tile kt resident
        u16* bufA = lds + ((kt & 1) << 14);
        u16* bufB = bufA + 8192;
#pragma unroll
        for (int kk = 0; kk < 2; ++kk) {
            sh8 af[4], bf[4];
            const int g = kk * 4 + fq;
#pragma unroll
            for (int i = 0; i < 4; ++i) {
                const int m = wm + i * 16 + fr;
                af[i] = *(const sh8*)(bufA + ((size_t)m * 8 + (g ^ (m & 7))) * 8);
                const int n = wn + i * 16 + fr;
                bf[i] = *(const sh8*)(bufB + ((size_t)n * 8 + (g ^ (n & 7))) * 8);
            }
#pragma unroll
            for (int i = 0; i < 4; ++i) {
#pragma unroll
                for (int j = 0; j < 4; ++j)
                    acc[i][j] = __builtin_amdgcn_mfma_f32_16x16x32_bf16(af[i], bf[j], acc[i][j], 0, 0, 0);
                if (RS)
                    rsacc[i] = __builtin_amdgcn_mfma_f32_16x16x32_bf16(af[i], ones, rsacc[i], 0, 0, 0);
            }
        }
        barrier_raw();                       // all waves done reading buf[kt&1]
        if (kt + 2 < nk64) issue(kt + 2);
    }
}

// --------------------- conversions (fused) ----------------------------------
// blocks [0,8192): x fp32 -> bf16.  blocks [8192,8960): W -> W^T bf16 (x3).
__global__ __launch_bounds__(256) void cvt_all(
    const float* __restrict__ x,
    const float* __restrict__ Wq, const float* __restrict__ Wk, const float* __restrict__ Wv,
    u16* __restrict__ xb, u16* __restrict__ wt)
{
    __shared__ float tile[64][68];
    const int bid = blockIdx.x;
    if (bid < 8192) {
        size_t i = ((size_t)bid * 256 + threadIdx.x) * 4;
        float4 f = *(const float4*)(x + i);
        ushort4 o;
        o.x = f2bf(f.x); o.y = f2bf(f.y); o.z = f2bf(f.z); o.w = f2bf(f.w);
        *(ushort4*)(xb + i) = o;
        return;
    }
    const int r = bid - 8192;
    const int z = r >> 8;                  // 0..2
    const int rr = r & 255;
    const int n0 = (rr & 15) * 64, k0 = (rr >> 4) * 64;
    const float* W = z == 0 ? Wq : (z == 1 ? Wk : Wv);
    u16* out = wt + (size_t)z * C_ * C_;
    const int tx = threadIdx.x & 15, ty = threadIdx.x >> 4;
#pragma unroll
    for (int rr2 = 0; rr2 < 4; ++rr2) {
        int row = ty + rr2 * 16;
        *(float4*)&tile[row][tx * 4] = *(const float4*)(W + (size_t)(k0 + row) * C_ + n0 + tx * 4);
    }
    __syncthreads();
#pragma unroll
    for (int rr2 = 0; rr2 < 4; ++rr2) {
        int n = ty + rr2 * 16;
        ushort4 o;
        o.x = f2bf(tile[tx * 4 + 0][n]);
        o.y = f2bf(tile[tx * 4 + 1][n]);
        o.z = f2bf(tile[tx * 4 + 2][n]);
        o.w = f2bf(tile[tx * 4 + 3][n]);
        *(ushort4*)(out + (size_t)(n0 + n) * C_ + k0 + tx * 4) = o;
    }
}

// ---------------------------------------------------------------------------
// q/k/v projections, 256x256 tile, 8 waves (2M x 4N), 8-phase schedule.
//   Ring: 4 slots x (A 256x32 + B 256x32) bf16 = 4 x 32KB = 128 KB LDS.
//   Slice sk consumed in 2 phases (j-half 0, j-half 1); per phase:
//     { ds_read frags ; issue half-slice stage for slice sk+3 ; barrier ;
//       setprio(1) ; 16 MFMA ; setprio(0) ; [vmcnt(8) end of jh=1] ; barrier }
//   vmcnt(8) leaves slices sk+2,sk+3 (8 loads) in flight -> slice sk+1
//   resident; 4 phases (~1400 cyc) of HBM latency cover. Never drains to 0
//   until the final slices (vm4/vm0 tail).
//   Swizzle: within a 32-col slice (4 x 16B granules/row), phys granule
//   pg = lg ^ ((row>>1)&3), applied on the gload source (LDS dest linear,
//   rule both-sides-or-neither); ds_read_b128 sees 2-way aliasing = free.
//   Grid 384 (= 3z x 32m x 4n), bijective XCD swizzle (384 % 8 == 0).
// ---------------------------------------------------------------------------
__global__ __launch_bounds__(512, 2) void qkv8(
    const u16* __restrict__ xb, const u16* __restrict__ wt,
    const float* __restrict__ bq, const float* __restrict__ bk, const float* __restrict__ bv,
    u16* __restrict__ qo, u16* __restrict__ ko, u16* __restrict__ vto)
{
    __shared__ __align__(16) u16 smem[65536];   // 128 KB ring / epilogue bounce
    const int bid = blockIdx.x;
    const int wg  = (bid & 7) * 48 + (bid >> 3);  // XCD swizzle, bijective
    const int z   = wg >> 7;                      // 0..2
    const int tt  = wg & 127;
    const int n0  = (tt >> 5) << 8;               // 0..768
    const int m0  = (tt & 31) << 8;               // 0..7936 (consecutive wg share B panel)
    const int tid = threadIdx.x;

    const u16* Ag = xb + (size_t)m0 * C_;
    const u16* Bg = wt + (size_t)z * C_ * C_ + (size_t)n0 * C_;

    const int l  = tid & 63, w = tid >> 6;
    const int fr = l & 15,  fq = l >> 4;
    const int wm = (w >> 2) << 7;     // 0 / 128
    const int wn = (w & 3) << 6;      // 0 / 64 / 128 / 192

    // staging geometry: thread fills phys granules tid and tid+512 of a slice
    const int srow = tid >> 2, spg = tid & 3;
    const int slg  = spg ^ ((srow >> 1) & 3);     // logical granule to fetch
    const u16* aS0 = Ag + (size_t)srow * C_ + slg * 8;
    const u16* aS1 = Ag + (size_t)(srow + 128) * C_ + slg * 8;
    const u16* bS0 = Bg + (size_t)srow * C_ + slg * 8;
    const u16* bS1 = Bg + (size_t)(srow + 128) * C_ + slg * 8;

    auto stageA = [&](int sl) {
        u16* d = smem + ((sl & 3) << 14);
        gload_lds16(aS0 + sl * 32, d + tid * 8);
        gload_lds16(aS1 + sl * 32, d + 4096 + tid * 8);
    };
    auto stageB = [&](int sl) {
        u16* d = smem + ((sl & 3) << 14) + 8192;
        gload_lds16(bS0 + sl * 32, d + tid * 8);
        gload_lds16(bS1 + sl * 32, d + 4096 + tid * 8);
    };

    f32x4 acc[8][4];
#pragma unroll
    for (int i = 0; i < 8; ++i)
#pragma unroll
        for (int j = 0; j < 4; ++j) acc[i][j] = 0.0f;

    // prologue: slices 0,1,2 in flight (12 loads/thread)
    stageA(0); stageB(0);
    stageA(1); stageB(1);
    stageA(2); stageB(2);
    wait_vm8();                         // slice 0 resident (8 newest = slices 1,2)
    barrier_raw();

#pragma unroll 4
    for (int sk = 0; sk < 32; ++sk) {
        const u16* bA = smem + ((sk & 3) << 14);
        const u16* bB = bA + 8192;
        sh8 af[8], bf[2];
        // ---- phase jh=0: A frags (reused across both phases) + B j=0,1 ----
#pragma unroll
        for (int i = 0; i < 8; ++i) {
            const int m = wm + i * 16 + fr;
            af[i] = *(const sh8*)(bA + ((m << 2) + (fq ^ ((m >> 1) & 3))) * 8);
        }
#pragma unroll
        for (int jj = 0; jj < 2; ++jj) {
            const int n = wn + jj * 16 + fr;
            bf[jj] = *(const sh8*)(bB + ((n << 2) + (fq ^ ((n >> 1) & 3))) * 8);
        }
        if (sk + 3 < 32) stageA(sk + 3);   // slot (sk+3)&3 freed at end of slice sk-1
        barrier_raw();
        __builtin_amdgcn_s_setprio(1);
#pragma unroll
        for (int i = 0; i < 8; ++i) {
            acc[i][0] = __builtin_amdgcn_mfma_f32_16x16x32_bf16(af[i], bf[0], acc[i][0], 0, 0, 0);
            acc[i][1] = __builtin_amdgcn_mfma_f32_16x16x32_bf16(af[i], bf[1], acc[i][1], 0, 0, 0);
        }
        __builtin_amdgcn_s_setprio(0);
        barrier_raw();
        // ---- phase jh=1: B j=2,3 ----
#pragma unroll
        for (int jj = 0; jj < 2; ++jj) {
            const int n = wn + (2 + jj) * 16 + fr;
            bf[jj] = *(const sh8*)(bB + ((n << 2) + (fq ^ ((n >> 1) & 3))) * 8);
        }
        if (sk + 3 < 32) stageB(sk + 3);
        barrier_raw();
        __builtin_amdgcn_s_setprio(1);
#pragma unroll
        for (int i = 0; i < 8; ++i) {
            acc[i][2] = __builtin_amdgcn_mfma_f32_16x16x32_bf16(af[i], bf[0], acc[i][2], 0, 0, 0);
            acc[i][3] = __builtin_amdgcn_mfma_f32_16x16x32_bf16(af[i], bf[1], acc[i][3], 0, 0, 0);
        }
        __builtin_amdgcn_s_setprio(0);
        if      (sk + 3 < 32) wait_vm8();   // slice sk+1 resident for next iter
        else if (sk + 2 < 32) wait_vm4();
        else if (sk + 1 < 32) wait_vm0();
        barrier_raw();
    }

    // ---- epilogue: acc -> swizzled 256x256 bf16 bounce (ring reused) ----
    // element (row,col); phys granule = (col>>3) ^ ((row>>3)&31) (bijective/row)
    const float* bias = z == 0 ? bq : (z == 1 ? bk : bv);
#pragma unroll
    for (int j = 0; j < 4; ++j) {
        const int col = wn + j * 16 + fr;
        const float bb = bias[n0 + col];
        const int cg = col >> 3, ce = col & 7;
#pragma unroll
        for (int i = 0; i < 8; ++i)
#pragma unroll
            for (int r = 0; r < 4; ++r) {
                const int row = wm + i * 16 + fq * 4 + r;
                smem[row * 256 + ((cg ^ ((row >> 3) & 31)) << 3) + ce] = f2bf(acc[i][j][r] + bb);
            }
    }
    __syncthreads();

    if (z < 2) {
        u16* out = z == 0 ? qo : ko;
#pragma unroll
        for (int p = 0; p < 16; ++p) {
            const int idx = p * 512 + tid;
            const int row = idx >> 5;          // 0..255
            const int c16 = idx & 31;          // uint4 index within row
            uint4 v = *(const uint4*)&smem[row * 256 + ((c16 ^ ((row >> 3) & 31)) << 3)];
            *(uint4*)(out + (size_t)(m0 + row) * C_ + n0 + c16 * 8) = v;
        }
    } else {
        const int b  = m0 >> 11;
        const int t0 = m0 & 2047;
        u16* vt = vto + (size_t)b * C_ * T_;
#pragma unroll
        for (int p = 0; p < 16; ++p) {
            const int idx = p * 512 + tid;
            const int cl = idx >> 5;           // channel within tile (0..255)
            const int ch = idx & 31;           // t-chunk (8 elems)
            const int cg = cl >> 3, ce = cl & 7;
            u16 tmp[8];
#pragma unroll
            for (int e = 0; e < 8; ++e) {
                const int row = ch * 8 + e;
                tmp[e] = smem[row * 256 + ((cg ^ ((row >> 3) & 31)) << 3) + ce];
            }
            *(uint4*)(vt + (size_t)(n0 + cl) * T_ + t0 + ch * 8) = *(uint4*)tmp;
        }
    }
}

// att per-batch offsets in u16 units: b0,b1 over xb region; b2,b3 over wt region.
__device__ __constant__ size_t att_off[4] = {
    0, (size_t)1 << 22, (size_t)1 << 25, ((size_t)1 << 25) + ((size_t)1 << 22)
};

// --------------------- scores: P = exp(q k^T / 32), causal ------------------
// grid (136, 1, 4): flattened lower-triangle tile index x batch.
__global__ __launch_bounds__(256, 2) void scores_mfma(
    const u16* __restrict__ qb, const u16* __restrict__ kb, u16* __restrict__ wsbase)
{
    int t = blockIdx.x;
    int by = (int)((sqrtf(8.f * t + 1.f) - 1.f) * 0.5f);
    while ((by + 1) * (by + 2) / 2 <= t) ++by;
    while (by * (by + 1) / 2 > t) --by;
    const int bx = t - by * (by + 1) / 2;
    const int b = blockIdx.z;
    const int s0 = bx * 128, m0 = by * 128;
    __shared__ __align__(16) u16 smem[32768];
    const u16* Q = qb + (size_t)b * T_ * C_ + (size_t)m0 * C_;
    const u16* K = kb + (size_t)b * T_ * C_ + (size_t)s0 * C_;
    const int tid = threadIdx.x;
    f32x4 acc[4][4];
#pragma unroll
    for (int i = 0; i < 4; ++i)
#pragma unroll
        for (int j = 0; j < 4; ++j) acc[i][j] = 0.0f;

    mm_core<false>(Q, K, C_, C_, C_ / 64, smem, acc, nullptr, tid);

    const int w = tid >> 6, l = tid & 63, fr = l & 15, fq = l >> 4;
    const int wm = (w & 1) << 6, wn = (w >> 1) << 6;
#pragma unroll
    for (int i = 0; i < 4; ++i)
#pragma unroll
        for (int r = 0; r < 4; ++r) {
            const int lm = wm + i * 16 + fq * 4 + r;
            const int m = m0 + lm;
#pragma unroll
            for (int j = 0; j < 4; ++j) {
                const int ls = wn + j * 16 + fr;
                const int s = s0 + ls;
                float e = (s <= m) ? __expf(acc[i][j][r] * 0.03125f) : 0.f;
                smem[lm * 136 + ls] = f2bf(e);
            }
        }
    __syncthreads();
    u16* att = wsbase + att_off[b] + (size_t)m0 * T_ + s0;
    const int rr = tid >> 4, cc = tid & 15;
#pragma unroll
    for (int p = 0; p < 8; ++p) {
        const int row = p * 16 + rr;
        uint4 val = *(const uint4*)&smem[row * 136 + cc * 8];
        *(uint4*)(att + (size_t)row * T_ + cc * 8) = val;
    }
}

// --------------------- O = (P v) / rowsum -----------------------------------
// grid (8, 16, 4), heavy m-tiles first. Rowsum via MFMA-with-ones in mm_core.
__global__ __launch_bounds__(256, 2) void pv_mfma(
    const u16* __restrict__ wsbase, const u16* __restrict__ vt,
    float* __restrict__ outp)
{
    const int b = blockIdx.z;
    const int n0 = blockIdx.x * 128;
    const int by = 15 - blockIdx.y;            // heavy (long-K) tiles first
    const int m0 = by * 128;
    __shared__ __align__(16) u16 smem[32768];
    const u16* A  = wsbase + att_off[b] + (size_t)m0 * T_;
    const u16* Bp = vt + (size_t)b * C_ * T_ + (size_t)n0 * T_;
    const int tid = threadIdx.x;
    f32x4 acc[4][4], rs[4];
#pragma unroll
    for (int i = 0; i < 4; ++i) {
        rs[i] = 0.0f;
#pragma unroll
        for (int j = 0; j < 4; ++j) acc[i][j] = 0.0f;
    }

    mm_core<true>(A, Bp, T_, T_, (m0 + 128) >> 6, smem, acc, rs, tid);

    const int w = tid >> 6, l = tid & 63, fr = l & 15, fq = l >> 4;
    const int wm = (w & 1) << 6, wn = (w >> 1) << 6;
    float* fb = (float*)smem;                  // 64 x 132 f32 bounce
#pragma unroll
    for (int p = 0; p < 2; ++p) {
        if ((w & 1) == p) {
#pragma unroll
            for (int i = 0; i < 4; ++i)
#pragma unroll
                for (int r = 0; r < 4; ++r) {
                    const int rr2 = i * 16 + fq * 4 + r;
                    const float inv = 1.0f / rs[i][r];
#pragma unroll
                    for (int j = 0; j < 4; ++j)
                        fb[rr2 * 132 + wn + j * 16 + fr] = acc[i][j][r] * inv;
                }
        }
        __syncthreads();
        const int rr = tid >> 5, cc = (tid & 31) * 4;
#pragma unroll
        for (int k2 = 0; k2 < 8; ++k2) {
            const int row = k2 * 8 + rr;
            float4 val = *(const float4*)&fb[row * 132 + cc];
            *(float4*)(outp + ((size_t)b * T_ + m0 + p * 64 + row) * C_ + n0 + cc) = val;
        }
        __syncthreads();
    }
}

extern "C" void kernel_launch(void* const* d_in, const int* in_sizes, int n_in,
                              void* d_out, int out_size, void* d_ws, size_t ws_size,
                              hipStream_t stream) {
    const float* x  = (const float*)d_in[0];
    const float* Wq = (const float*)d_in[1];
    const float* bq = (const float*)d_in[2];
    const float* Wk = (const float*)d_in[3];
    const float* bk = (const float*)d_in[4];
    const float* Wv = (const float*)d_in[5];
    const float* bv = (const float*)d_in[6];
    float* out = (float*)d_out;

    // workspace (80 MB):
    //   [ 0,16M) xb   -> dead after qkv; att batches 0,1 overlay
    //   [16,32M) q
    //   [32,48M) k
    //   [48,64M) vt   (v transposed [b][c][t])
    //   [64,70M) wt   -> dead after qkv; att batches 2,3 overlay [64,80M)
    char* ws = (char*)d_ws;
    u16* xb   = (u16*)ws;
    u16* q    = (u16*)(ws + (16ull << 20));
    u16* k    = (u16*)(ws + (32ull << 20));
    u16* vt   = (u16*)(ws + (48ull << 20));
    u16* wt   = (u16*)(ws + (64ull << 20));
    u16* attb = (u16*)ws;   // att_off[] indexes from workspace base

    cvt_all <<<8960, 256, 0, stream>>>(x, Wq, Wk, Wv, xb, wt);
    qkv8    <<<384, 512, 0, stream>>>(xb, wt, bq, bk, bv, q, k, vt);
    scores_mfma<<<dim3(136, 1, 4), 256, 0, stream>>>(q, k, attb);
    pv_mfma    <<<dim3(8, 16, 4), 256, 0, stream>>>(attb, vt, out);
}

// Round 2
// 247.191 us; speedup vs baseline: 1.0036x; 1.0036x over previous
//
#include <hip/hip_runtime.h>

#define B_ 4
#define T_ 2048
#define C_ 1024

typedef unsigned short u16;
typedef unsigned int u32;
typedef short sh8 __attribute__((ext_vector_type(8)));   // 8 bf16 payload (4 VGPRs)
typedef float f32x4 __attribute__((ext_vector_type(4)));

__device__ __forceinline__ float bf2f(u16 u) {
    union { float f; u32 i; } c; c.i = ((u32)u) << 16; return c.f;
}
__device__ __forceinline__ u16 f2bf(float f) {
    union { float f; u32 i; } c; c.f = f;
    return (u16)((c.i + 0x7FFFu + ((c.i >> 16) & 1u)) >> 16);
}

// async 16B/lane global->LDS. Dest = wave-uniform base + lane*16.
__device__ __forceinline__ void gload_lds16(const void* g, void* l) {
    __builtin_amdgcn_global_load_lds(
        (const __attribute__((address_space(1))) u32*)g,
        (__attribute__((address_space(3))) u32*)l, 16, 0, 0);
}

__device__ __forceinline__ void wait_vm10()  { asm volatile("s_waitcnt vmcnt(10)" ::: "memory"); }
__device__ __forceinline__ void wait_vm8()   { asm volatile("s_waitcnt vmcnt(8)" ::: "memory"); }
__device__ __forceinline__ void wait_vm5()   { asm volatile("s_waitcnt vmcnt(5)" ::: "memory"); }
__device__ __forceinline__ void wait_vm0()   { asm volatile("s_waitcnt vmcnt(0)" ::: "memory"); }
__device__ __forceinline__ void barrier_raw(){ asm volatile("s_barrier" ::: "memory"); }

// ---------------------------------------------------------------------------
// 128x128 TN MFMA core (scores/pv), bf16, BK=64, double-buffered
// global_load_lds with counted vmcnt(8).
// ---------------------------------------------------------------------------
template<bool RS>
__device__ __forceinline__ void mm_core(
    const u16* __restrict__ A, const u16* __restrict__ B,
    int ldA, int ldB, int nk64,
    u16* lds, f32x4 (&acc)[4][4], f32x4* rsacc, int tid)
{
    const int w  = tid >> 6, l = tid & 63;
    const int fr = l & 15,  fq = l >> 4;
    const int wm = (w & 1) << 6, wn = (w >> 1) << 6;
    const int rl = l >> 3;            // row within 8-row group
    const int pc = l & 7;             // phys granule col this lane fills
    const int cg = pc ^ rl;           // logical granule to fetch

    sh8 ones;
    if (RS) {
#pragma unroll
        for (int e = 0; e < 8; ++e) ones[e] = (short)0x3F80;  // bf16 1.0
    }

    auto issue = [&](int kt) {
        const int ko = kt << 6;
        u16* dA = lds + ((kt & 1) << 14);
        u16* dB = dA + 8192;
#pragma unroll
        for (int t = 0; t < 4; ++t) {
            const int r0 = w * 32 + t * 8;
            const int r  = r0 + rl;
            gload_lds16(A + (size_t)r * ldA + ko + cg * 8, dA + ((size_t)r0 * 8 + l) * 8);
            gload_lds16(B + (size_t)r * ldB + ko + cg * 8, dB + ((size_t)r0 * 8 + l) * 8);
        }
    };

    issue(0);
    issue(1);

    for (int kt = 0; kt < nk64; ++kt) {
        if (kt + 1 < nk64) wait_vm8(); else wait_vm0();
        barrier_raw();                       // block-wide: tile kt resident
        u16* bufA = lds + ((kt & 1) << 14);
        u16* bufB = bufA + 8192;
#pragma unroll
        for (int kk = 0; kk < 2; ++kk) {
            sh8 af[4], bf[4];
            const int g = kk * 4 + fq;
#pragma unroll
            for (int i = 0; i < 4; ++i) {
                const int m = wm + i * 16 + fr;
                af[i] = *(const sh8*)(bufA + ((size_t)m * 8 + (g ^ (m & 7))) * 8);
                const int n = wn + i * 16 + fr;
                bf[i] = *(const sh8*)(bufB + ((size_t)n * 8 + (g ^ (n & 7))) * 8);
            }
#pragma unroll
            for (int i = 0; i < 4; ++i) {
#pragma unroll
                for (int j = 0; j < 4; ++j)
                    acc[i][j] = __builtin_amdgcn_mfma_f32_16x16x32_bf16(af[i], bf[j], acc[i][j], 0, 0, 0);
                if (RS)
                    rsacc[i] = __builtin_amdgcn_mfma_f32_16x16x32_bf16(af[i], ones, rsacc[i], 0, 0, 0);
            }
        }
        barrier_raw();                       // all waves done reading buf[kt&1]
        if (kt + 2 < nk64) issue(kt + 2);
    }
}

// --------------------- conversions (fused) ----------------------------------
// blocks [0,8192): x fp32 -> bf16.  blocks [8192,8960): W -> W^T bf16 (x3).
__global__ __launch_bounds__(256) void cvt_all(
    const float* __restrict__ x,
    const float* __restrict__ Wq, const float* __restrict__ Wk, const float* __restrict__ Wv,
    u16* __restrict__ xb, u16* __restrict__ wt)
{
    __shared__ float tile[64][68];
    const int bid = blockIdx.x;
    if (bid < 8192) {
        size_t i = ((size_t)bid * 256 + threadIdx.x) * 4;
        float4 f = *(const float4*)(x + i);
        ushort4 o;
        o.x = f2bf(f.x); o.y = f2bf(f.y); o.z = f2bf(f.z); o.w = f2bf(f.w);
        *(ushort4*)(xb + i) = o;
        return;
    }
    const int r = bid - 8192;
    const int z = r >> 8;                  // 0..2
    const int rr = r & 255;
    const int n0 = (rr & 15) * 64, k0 = (rr >> 4) * 64;
    const float* W = z == 0 ? Wq : (z == 1 ? Wk : Wv);
    u16* out = wt + (size_t)z * C_ * C_;
    const int tx = threadIdx.x & 15, ty = threadIdx.x >> 4;
#pragma unroll
    for (int rr2 = 0; rr2 < 4; ++rr2) {
        int row = ty + rr2 * 16;
        *(float4*)&tile[row][tx * 4] = *(const float4*)(W + (size_t)(k0 + row) * C_ + n0 + tx * 4);
    }
    __syncthreads();
#pragma unroll
    for (int rr2 = 0; rr2 < 4; ++rr2) {
        int n = ty + rr2 * 16;
        ushort4 o;
        o.x = f2bf(tile[tx * 4 + 0][n]);
        o.y = f2bf(tile[tx * 4 + 1][n]);
        o.z = f2bf(tile[tx * 4 + 2][n]);
        o.w = f2bf(tile[tx * 4 + 3][n]);
        *(ushort4*)(out + (size_t)(n0 + n) * C_ + k0 + tx * 4) = o;
    }
}

// ---------------------------------------------------------------------------
// q/k/v projections, merged-N GEMM: C[8192 x 3072] = xb[8192x1024] * wt^T.
//   Tile 128(M) x 192(N), 256 threads (4 waves, 2M x 2N: per-wave 64x96).
//   Grid 64*16 = 1024 blocks = EXACTLY 2 passes at 2 blocks/CU (512 slots).
//   LDS ring: 4 slots x (A 128x32 + B 192x32) = 4 x 20KB = 80 KB -> 2 blk/CU.
//   Staging: 5 wave-loads/slice (2 A + 3 B), issued 3 slices ahead;
//   steady-state wait vmcnt(10) (slices sk+2, sk+3 in flight), never 0
//   until tail. Granule swizzle pg = lg ^ ((row>>1)&3) applied on global
//   source (LDS linear); frag ds_read_b128 sees free 2-way aliasing.
//   Epilogue: 128x192 LDS bounce (stride 200), per-16-col-group routing to
//   q/k (row-major) or v (transposed vt[b][c][t]).
// ---------------------------------------------------------------------------
__global__ __launch_bounds__(256, 2) void qkv_p(
    const u16* __restrict__ xb, const u16* __restrict__ wt,
    const float* __restrict__ bq, const float* __restrict__ bk, const float* __restrict__ bv,
    u16* __restrict__ qo, u16* __restrict__ ko, u16* __restrict__ vto)
{
    __shared__ __align__(16) u16 smem[40960];   // 80 KB: 4 x 10240 u16 slots
    const int bid = blockIdx.x;
    const int wg  = (bid & 7) * 128 + (bid >> 3);  // XCD swizzle (1024%8==0)
    const int mt  = wg >> 4;                       // 0..63
    const int nt  = wg & 15;                       // 0..15
    const int m0  = mt << 7;
    const int n0  = nt * 192;
    const int tid = threadIdx.x;

    const u16* Ag = xb + (size_t)m0 * C_;
    const u16* Bg = wt + (size_t)n0 * C_;

    const int l  = tid & 63, w = tid >> 6;
    const int fr = l & 15,  fq = l >> 4;
    const int wm = (w & 1) << 6;          // 0 / 64
    const int wn = (w >> 1) * 96;         // 0 / 96

    // staging geometry: granule gi = p*256 + tid; row = gi>>2, phys col gi&3
    const int srow = tid >> 2, spg = tid & 3;
    // per-part rows: A parts p=0,1 -> rows srow, srow+64; B parts p=0,1,2
    const int rA0 = srow,      rA1 = srow + 64;
    const int rB0 = srow,      rB1 = srow + 64, rB2 = srow + 128;
    const int lgA0 = spg ^ ((rA0 >> 1) & 3), lgA1 = spg ^ ((rA1 >> 1) & 3);
    const int lgB0 = lgA0, lgB1 = lgA1, lgB2 = spg ^ ((rB2 >> 1) & 3);
    const u16* aS0 = Ag + (size_t)rA0 * C_ + lgA0 * 8;
    const u16* aS1 = Ag + (size_t)rA1 * C_ + lgA1 * 8;
    const u16* bS0 = Bg + (size_t)rB0 * C_ + lgB0 * 8;
    const u16* bS1 = Bg + (size_t)rB1 * C_ + lgB1 * 8;
    const u16* bS2 = Bg + (size_t)rB2 * C_ + lgB2 * 8;

    auto stageA = [&](int sl) {
        u16* d = smem + (size_t)(sl & 3) * 10240;
        gload_lds16(aS0 + sl * 32, d + tid * 8);
        gload_lds16(aS1 + sl * 32, d + 2048 + tid * 8);
    };
    auto stageB = [&](int sl) {
        u16* d = smem + (size_t)(sl & 3) * 10240 + 4096;
        gload_lds16(bS0 + sl * 32, d + tid * 8);
        gload_lds16(bS1 + sl * 32, d + 2048 + tid * 8);
        gload_lds16(bS2 + sl * 32, d + 4096 + tid * 8);
    };

    f32x4 acc[4][6];
#pragma unroll
    for (int i = 0; i < 4; ++i)
#pragma unroll
        for (int j = 0; j < 6; ++j) acc[i][j] = 0.0f;

    // prologue: slices 0,1,2 in flight (15 wave-loads)
    stageA(0); stageB(0);
    stageA(1); stageB(1);
    stageA(2); stageB(2);
    wait_vm10();                        // slice 0 resident
    barrier_raw();

#pragma unroll 4
    for (int sk = 0; sk < 32; ++sk) {
        const u16* sA = smem + (size_t)(sk & 3) * 10240;
        const u16* sB = sA + 4096;
        sh8 af[4], bf[3];
        // ---- phase 0: A frags (live across both phases) + B j=0..2 ----
#pragma unroll
        for (int i = 0; i < 4; ++i) {
            const int m = wm + i * 16 + fr;
            af[i] = *(const sh8*)(sA + ((m << 2) + (fq ^ ((m >> 1) & 3))) * 8);
        }
#pragma unroll
        for (int jj = 0; jj < 3; ++jj) {
            const int n = wn + jj * 16 + fr;
            bf[jj] = *(const sh8*)(sB + ((n << 2) + (fq ^ ((n >> 1) & 3))) * 8);
        }
        if (sk + 3 < 32) stageA(sk + 3);
        barrier_raw();
        __builtin_amdgcn_s_setprio(1);
#pragma unroll
        for (int i = 0; i < 4; ++i) {
            acc[i][0] = __builtin_amdgcn_mfma_f32_16x16x32_bf16(af[i], bf[0], acc[i][0], 0, 0, 0);
            acc[i][1] = __builtin_amdgcn_mfma_f32_16x16x32_bf16(af[i], bf[1], acc[i][1], 0, 0, 0);
            acc[i][2] = __builtin_amdgcn_mfma_f32_16x16x32_bf16(af[i], bf[2], acc[i][2], 0, 0, 0);
        }
        __builtin_amdgcn_s_setprio(0);
        barrier_raw();
        // ---- phase 1: B j=3..5 ----
#pragma unroll
        for (int jj = 0; jj < 3; ++jj) {
            const int n = wn + (3 + jj) * 16 + fr;
            bf[jj] = *(const sh8*)(sB + ((n << 2) + (fq ^ ((n >> 1) & 3))) * 8);
        }
        if (sk + 3 < 32) stageB(sk + 3);
        barrier_raw();
        __builtin_amdgcn_s_setprio(1);
#pragma unroll
        for (int i = 0; i < 4; ++i) {
            acc[i][3] = __builtin_amdgcn_mfma_f32_16x16x32_bf16(af[i], bf[0], acc[i][3], 0, 0, 0);
            acc[i][4] = __builtin_amdgcn_mfma_f32_16x16x32_bf16(af[i], bf[1], acc[i][4], 0, 0, 0);
            acc[i][5] = __builtin_amdgcn_mfma_f32_16x16x32_bf16(af[i], bf[2], acc[i][5], 0, 0, 0);
        }
        __builtin_amdgcn_s_setprio(0);
        if      (sk < 29) wait_vm10();     // slice sk+1 resident for next iter
        else if (sk == 29) wait_vm5();
        else if (sk == 30) wait_vm0();
        barrier_raw();
    }

    // ---- epilogue: acc -> 128x192 LDS bounce (stride 200), routed stores ----
    u16* bb = smem;
#pragma unroll
    for (int j = 0; j < 6; ++j) {
        const int col = wn + j * 16 + fr;
        const int gc  = n0 + col;
        const int z   = gc >> 10;
        const int cw  = gc & 1023;
        const float bv_ = (z == 0 ? bq : (z == 1 ? bk : bv))[cw];
#pragma unroll
        for (int i = 0; i < 4; ++i)
#pragma unroll
            for (int r = 0; r < 4; ++r) {
                const int row = wm + i * 16 + fq * 4 + r;
                bb[row * 200 + col] = f2bf(acc[i][j][r] + bv_);
            }
    }
    __syncthreads();

    // q/k store: 2 threads per row, 12 x uint4 chunks each
    {
        const int r    = tid >> 1;
        const int half = tid & 1;
#pragma unroll
        for (int q = 0; q < 12; ++q) {
            const int c8  = half * 12 + q;          // 0..23
            const int gc0 = n0 + c8 * 8;
            const int z   = gc0 >> 10;
            if (z < 2) {
                uint4 v = *(const uint4*)&bb[r * 200 + c8 * 8];
                u16* out = z == 0 ? qo : ko;
                *(uint4*)(out + (size_t)(m0 + r) * C_ + (gc0 & 1023)) = v;
            }
        }
    }
    // v store (transposed): per 16-col group with gc >= 2048
    {
        const int bidx = m0 >> 11;
        const int t0   = m0 & 2047;
        u16* vt = vto + (size_t)bidx * C_ * T_;
#pragma unroll
        for (int g = 0; g < 12; ++g) {
            const int gc0 = n0 + g * 16;
            if (gc0 >= 2048) {
                const int col   = g * 16 + (tid >> 4);
                const int chunk = tid & 15;
                const int c     = (n0 + col) - 2048;
                u16 tmp[8];
#pragma unroll
                for (int e = 0; e < 8; ++e)
                    tmp[e] = bb[(chunk * 8 + e) * 200 + col];
                *(uint4*)(vt + (size_t)c * T_ + t0 + chunk * 8) = *(uint4*)tmp;
            }
        }
    }
}

// att per-batch offsets in u16 units: b0,b1 over xb region; b2,b3 over wt region.
__device__ __constant__ size_t att_off[4] = {
    0, (size_t)1 << 22, (size_t)1 << 25, ((size_t)1 << 25) + ((size_t)1 << 22)
};

// --------------------- scores: P = exp(q k^T / 32), causal ------------------
// grid (136, 1, 4): flattened lower-triangle tile index x batch.
__global__ __launch_bounds__(256, 2) void scores_mfma(
    const u16* __restrict__ qb, const u16* __restrict__ kb, u16* __restrict__ wsbase)
{
    int t = blockIdx.x;
    int by = (int)((sqrtf(8.f * t + 1.f) - 1.f) * 0.5f);
    while ((by + 1) * (by + 2) / 2 <= t) ++by;
    while (by * (by + 1) / 2 > t) --by;
    const int bx = t - by * (by + 1) / 2;
    const int b = blockIdx.z;
    const int s0 = bx * 128, m0 = by * 128;
    __shared__ __align__(16) u16 smem[32768];
    const u16* Q = qb + (size_t)b * T_ * C_ + (size_t)m0 * C_;
    const u16* K = kb + (size_t)b * T_ * C_ + (size_t)s0 * C_;
    const int tid = threadIdx.x;
    f32x4 acc[4][4];
#pragma unroll
    for (int i = 0; i < 4; ++i)
#pragma unroll
        for (int j = 0; j < 4; ++j) acc[i][j] = 0.0f;

    mm_core<false>(Q, K, C_, C_, C_ / 64, smem, acc, nullptr, tid);

    const int w = tid >> 6, l = tid & 63, fr = l & 15, fq = l >> 4;
    const int wm = (w & 1) << 6, wn = (w >> 1) << 6;
#pragma unroll
    for (int i = 0; i < 4; ++i)
#pragma unroll
        for (int r = 0; r < 4; ++r) {
            const int lm = wm + i * 16 + fq * 4 + r;
            const int m = m0 + lm;
#pragma unroll
            for (int j = 0; j < 4; ++j) {
                const int ls = wn + j * 16 + fr;
                const int s = s0 + ls;
                float e = (s <= m) ? __expf(acc[i][j][r] * 0.03125f) : 0.f;
                smem[lm * 136 + ls] = f2bf(e);
            }
        }
    __syncthreads();
    u16* att = wsbase + att_off[b] + (size_t)m0 * T_ + s0;
    const int rr = tid >> 4, cc = tid & 15;
#pragma unroll
    for (int p = 0; p < 8; ++p) {
        const int row = p * 16 + rr;
        uint4 val = *(const uint4*)&smem[row * 136 + cc * 8];
        *(uint4*)(att + (size_t)row * T_ + cc * 8) = val;
    }
}

// --------------------- O = (P v) / rowsum -----------------------------------
// grid (8, 16, 4), heavy m-tiles first. Rowsum via MFMA-with-ones in mm_core.
__global__ __launch_bounds__(256, 2) void pv_mfma(
    const u16* __restrict__ wsbase, const u16* __restrict__ vt,
    float* __restrict__ outp)
{
    const int b = blockIdx.z;
    const int n0 = blockIdx.x * 128;
    const int by = 15 - blockIdx.y;            // heavy (long-K) tiles first
    const int m0 = by * 128;
    __shared__ __align__(16) u16 smem[32768];
    const u16* A  = wsbase + att_off[b] + (size_t)m0 * T_;
    const u16* Bp = vt + (size_t)b * C_ * T_ + (size_t)n0 * T_;
    const int tid = threadIdx.x;
    f32x4 acc[4][4], rs[4];
#pragma unroll
    for (int i = 0; i < 4; ++i) {
        rs[i] = 0.0f;
#pragma unroll
        for (int j = 0; j < 4; ++j) acc[i][j] = 0.0f;
    }

    mm_core<true>(A, Bp, T_, T_, (m0 + 128) >> 6, smem, acc, rs, tid);

    const int w = tid >> 6, l = tid & 63, fr = l & 15, fq = l >> 4;
    const int wm = (w & 1) << 6, wn = (w >> 1) << 6;
    float* fb = (float*)smem;                  // 64 x 132 f32 bounce
#pragma unroll
    for (int p = 0; p < 2; ++p) {
        if ((w & 1) == p) {
#pragma unroll
            for (int i = 0; i < 4; ++i)
#pragma unroll
                for (int r = 0; r < 4; ++r) {
                    const int rr2 = i * 16 + fq * 4 + r;
                    const float inv = 1.0f / rs[i][r];
#pragma unroll
                    for (int j = 0; j < 4; ++j)
                        fb[rr2 * 132 + wn + j * 16 + fr] = acc[i][j][r] * inv;
                }
        }
        __syncthreads();
        const int rr = tid >> 5, cc = (tid & 31) * 4;
#pragma unroll
        for (int k2 = 0; k2 < 8; ++k2) {
            const int row = k2 * 8 + rr;
            float4 val = *(const float4*)&fb[row * 132 + cc];
            *(float4*)(outp + ((size_t)b * T_ + m0 + p * 64 + row) * C_ + n0 + cc) = val;
        }
        __syncthreads();
    }
}

extern "C" void kernel_launch(void* const* d_in, const int* in_sizes, int n_in,
                              void* d_out, int out_size, void* d_ws, size_t ws_size,
                              hipStream_t stream) {
    const float* x  = (const float*)d_in[0];
    const float* Wq = (const float*)d_in[1];
    const float* bq = (const float*)d_in[2];
    const float* Wk = (const float*)d_in[3];
    const float* bk = (const float*)d_in[4];
    const float* Wv = (const float*)d_in[5];
    const float* bv = (const float*)d_in[6];
    float* out = (float*)d_out;

    // workspace (80 MB):
    //   [ 0,16M) xb   -> dead after qkv; att batches 0,1 overlay
    //   [16,32M) q
    //   [32,48M) k
    //   [48,64M) vt   (v transposed [b][c][t])
    //   [64,70M) wt   -> dead after qkv; att batches 2,3 overlay [64,80M)
    char* ws = (char*)d_ws;
    u16* xb   = (u16*)ws;
    u16* q    = (u16*)(ws + (16ull << 20));
    u16* k    = (u16*)(ws + (32ull << 20));
    u16* vt   = (u16*)(ws + (48ull << 20));
    u16* wt   = (u16*)(ws + (64ull << 20));
    u16* attb = (u16*)ws;   // att_off[] indexes from workspace base

    cvt_all <<<8960, 256, 0, stream>>>(x, Wq, Wk, Wv, xb, wt);
    qkv_p   <<<1024, 256, 0, stream>>>(xb, wt, bq, bk, bv, q, k, vt);
    scores_mfma<<<dim3(136, 1, 4), 256, 0, stream>>>(q, k, attb);
    pv_mfma    <<<dim3(8, 16, 4), 256, 0, stream>>>(attb, vt, out);
}